// Round 1
// baseline (713.508 us; speedup 1.0000x reference)
//
#include <hip/hip_runtime.h>

// Shapes (fixed by the problem)
#define Bx 16
#define Cx 256
#define Dx 32
#define Nx 2304   // 48*48

typedef _Float16 f16;
typedef _Float16 f16x4 __attribute__((ext_vector_type(4)));
typedef _Float16 f16x8 __attribute__((ext_vector_type(8)));
typedef float    f32x4 __attribute__((ext_vector_type(4)));
typedef float    f32x16 __attribute__((ext_vector_type(16)));
typedef unsigned int u32x2 __attribute__((ext_vector_type(2)));
typedef unsigned int u32x4 __attribute__((ext_vector_type(4)));

// A,B fragment layouts (gfx950):
//  32x32x16_f16: lane holds A[m=lane%32][k=(lane/32)*8 + 0..7]  (f16x8)
//  C/D 32x32   : col=lane&31, row=(reg&3)+8*(reg>>2)+4*(lane>>5)  [guide-verified]
#define MFMA_K16(a, b, c) __builtin_amdgcn_mfma_f32_32x32x16_f16((a), (b), (c), 0, 0, 0)

// Repack two f16x4 B-frags of the K8 layout (j-granularity 4 per lane-half)
// into one f16x8 B-frag of the K16 layout (j-granularity 8 per lane-half).
// v_permlane32_swap_b32 swaps the UPPER 32 lanes of %0 with the LOWER 32 of %1:
//   a' = [a.lo | b.lo-from-partner]  -> frag elems 0..3 (k=8h+0..3)
//   b' = [a.hi-from-partner | b.hi]  -> frag elems 4..7 (k=8h+4..7)
__device__ __forceinline__ f16x8 swap_pack(f16x4 a, f16x4 b) {
    u32x2 au = __builtin_bit_cast(u32x2, a);
    u32x2 bu = __builtin_bit_cast(u32x2, b);
    unsigned a0 = au[0], a1 = au[1], b0 = bu[0], b1 = bu[1];
    asm("v_permlane32_swap_b32 %0, %1" : "+v"(a0), "+v"(b0));
    asm("v_permlane32_swap_b32 %0, %1" : "+v"(a1), "+v"(b1));
    u32x4 r = {a0, a1, b0, b1};
    return __builtin_bit_cast(f16x8, r);
}

// ---------------------------------------------------------------------------
// Kernel A: q/k projections -> f16 hi/lo, layout [b][n][d] (d contiguous).
// (unchanged — passed)
// ---------------------------------------------------------------------------
__global__ __launch_bounds__(256) void qk_proj(
    const float* __restrict__ x,
    const float* __restrict__ Wq, const float* __restrict__ bq,
    const float* __restrict__ Wk, const float* __restrict__ bk,
    f16* __restrict__ qhi, f16* __restrict__ qlo,
    f16* __restrict__ khi, f16* __restrict__ klo) {
    int bid = blockIdx.x;
    int nt = bid % 9;  bid /= 9;
    int dc = bid % 4;  bid /= 4;
    int b  = bid % Bx; bid /= Bx;
    int qk = bid;  // 0 -> q, 1 -> k
    const float* Wm   = qk ? Wk : Wq;
    const float* bias = qk ? bk : bq;
    f16* dhi          = qk ? khi : qhi;
    f16* dlo          = qk ? klo : qlo;

    int n  = nt * 256 + threadIdx.x;
    int d0 = dc * 8;
    float acc[8];
#pragma unroll
    for (int dd = 0; dd < 8; ++dd) acc[dd] = bias[d0 + dd];

    const float* xcol = x + (size_t)b * Cx * Nx + n;
    for (int c = 0; c < Cx; ++c) {
        float xv = xcol[(size_t)c * Nx];
#pragma unroll
        for (int dd = 0; dd < 8; ++dd)
            acc[dd] += Wm[(d0 + dd) * Cx + c] * xv;
    }
    f16x8 hi, lo;
#pragma unroll
    for (int dd = 0; dd < 8; ++dd) {
        f16 h = (f16)acc[dd];
        hi[dd] = h;
        lo[dd] = (f16)(acc[dd] - (float)h);
    }
    size_t base = ((size_t)b * Nx + n) * Dx + d0;
    *(f16x8*)(dhi + base) = hi;
    *(f16x8*)(dlo + base) = lo;
}

// ---------------------------------------------------------------------------
// Kernel B: v projection -> f16 hi/lo, layout [b][c][n] (n contiguous).
// (unchanged — passed)
// ---------------------------------------------------------------------------
__global__ __launch_bounds__(256) void v_proj(
    const float* __restrict__ x,
    const float* __restrict__ Wv, const float* __restrict__ bv,
    f16* __restrict__ vhi, f16* __restrict__ vlo) {
    __shared__ float sx[Cx * 16];
    int bid = blockIdx.x;
    int nt = bid % (Nx / 16);
    int b  = bid / (Nx / 16);
    int n0 = nt * 16;
    int t  = threadIdx.x;

    for (int r = 0; r < 16; ++r) {
        int f = r * 256 + t;
        int c = f >> 4, nn = f & 15;
        sx[f] = x[((size_t)b * Cx + c) * Nx + n0 + nn];
    }
    __syncthreads();

    float acc[16];
    float bvv = bv[t];
#pragma unroll
    for (int nn = 0; nn < 16; ++nn) acc[nn] = bvv;

    const float* wrow = Wv + (size_t)t * Cx;
    for (int c = 0; c < Cx; ++c) {
        float wv = wrow[c];
        const float4* sxr = (const float4*)&sx[c * 16];
#pragma unroll
        for (int g = 0; g < 4; ++g) {
            float4 xv = sxr[g];
            acc[g * 4 + 0] += wv * xv.x;
            acc[g * 4 + 1] += wv * xv.y;
            acc[g * 4 + 2] += wv * xv.z;
            acc[g * 4 + 3] += wv * xv.w;
        }
    }
    f16x8 h0, l0, h1, l1;
#pragma unroll
    for (int nn = 0; nn < 8; ++nn) {
        f16 h = (f16)acc[nn];
        h0[nn] = h; l0[nn] = (f16)(acc[nn] - (float)h);
    }
#pragma unroll
    for (int nn = 0; nn < 8; ++nn) {
        f16 h = (f16)acc[8 + nn];
        h1[nn] = h; l1[nn] = (f16)(acc[8 + nn] - (float)h);
    }
    size_t base = ((size_t)b * Cx + t) * Nx + n0;
    *(f16x8*)(vhi + base)     = h0;
    *(f16x8*)(vhi + base + 8) = h1;
    *(f16x8*)(vlo + base)     = l0;
    *(f16x8*)(vlo + base + 8) = l1;
}

// ---------------------------------------------------------------------------
// Kernel C: softmax column sums  s[b][j] = sum_i exp(E[i,j]).
// NEW: 4 waves per block, each covering 18 of the 72 i-tiles; deterministic
// LDS partial reduce. 4x wave count (1152 -> 4608 waves, ~18 waves/CU).
// grid: Bx * 72 blocks, 256 threads.
// ---------------------------------------------------------------------------
__global__ __launch_bounds__(256, 4) void col_stats(
    const f16* __restrict__ qhi, const f16* __restrict__ qlo,
    const f16* __restrict__ khi, const f16* __restrict__ klo,
    float* __restrict__ s) {
    __shared__ float part[4][32];
    int jt = blockIdx.x % 72;
    int b  = blockIdx.x / 72;
    int j0 = jt * 32;
    int t  = threadIdx.x;
    int w  = t >> 6;              // wave id 0..3
    int il = t & 31, h = (t >> 5) & 1;

    // K as A-operand: lane holds K[j0+il][d = h*8 + ks*16 + 0..7]
    f16x8 kh[2], kl[2];
#pragma unroll
    for (int ks = 0; ks < 2; ++ks) {
        size_t off = ((size_t)b * Nx + j0 + il) * Dx + h * 8 + ks * 16;
        kh[ks] = *(const f16x8*)(khi + off);
        kl[ks] = *(const f16x8*)(klo + off);
    }
    f32x16 sacc = {};
    for (int it = w * 18; it < w * 18 + 18; ++it) {
        f16x8 qh[2], ql[2];
#pragma unroll
        for (int ks = 0; ks < 2; ++ks) {
            size_t off = ((size_t)b * Nx + it * 32 + il) * Dx + h * 8 + ks * 16;
            qh[ks] = *(const f16x8*)(qhi + off);
            ql[ks] = *(const f16x8*)(qlo + off);
        }
        f32x16 e = {};
        __builtin_amdgcn_s_setprio(1);
        e = MFMA_K16(kh[0], qh[0], e);
        e = MFMA_K16(kh[0], ql[0], e);
        e = MFMA_K16(kl[0], qh[0], e);
        e = MFMA_K16(kh[1], qh[1], e);
        e = MFMA_K16(kh[1], ql[1], e);
        e = MFMA_K16(kl[1], qh[1], e);
        __builtin_amdgcn_s_setprio(0);
#pragma unroll
        for (int r = 0; r < 16; ++r) sacc[r] += __expf(e[r]);
    }
    // reduce across the 32 i-columns (xor<=16 stays within each 32-lane half)
#pragma unroll
    for (int r = 0; r < 16; ++r) {
        float v = sacc[r];
        for (int msk = 1; msk <= 16; msk <<= 1) v += __shfl_xor(v, msk);
        if (il == 0) part[w][(r & 3) + 8 * (r >> 2) + 4 * h] = v;
    }
    __syncthreads();
    if (t < 32)
        s[(size_t)b * Nx + j0 + t] =
            part[0][t] + part[1][t] + part[2][t] + part[3][t];
}

// ---------------------------------------------------------------------------
// Kernel D: main.  NEW structure:
//  - 128-thread blocks (2 waves). Wave w owns i-tile i0+32w; waves share the
//    rs[] LDS buffer. 4608 waves total (was 2304) -> 12 waves/CU @ lb(128,3).
//  - PV uses 32x32x16 MFMA (K8 runs at K16 cost on gfx950 -> was wasting half
//    the matrix pipe). P^T K8-frags are repacked to K16 frags with
//    v_permlane32_swap_b32 (2 swaps per frag pair); V is loaded as f16x8.
//    MFMA cost per wave-j-tile: 480 -> 288 CU-cycles.
// grid: Bx * 36 * 4 = 2304 blocks, 128 threads.
// ---------------------------------------------------------------------------
__global__ __launch_bounds__(128, 3) void attn_out(
    const f16* __restrict__ qhi, const f16* __restrict__ qlo,
    const f16* __restrict__ khi, const f16* __restrict__ klo,
    const f16* __restrict__ vhi, const f16* __restrict__ vlo,
    const float* __restrict__ s, const float* __restrict__ x,
    const float* __restrict__ gamma, float* __restrict__ out) {
    __shared__ __align__(16) float rs[Nx];   // 9216 B: 1/s for this batch
    int blk = blockIdx.x;
    int w4   = blk & 3;  blk >>= 2;     // c-quarter
    int it64 = blk % 36;
    int b    = blk / 36;
    int i0   = it64 * 64;
    int c0   = w4 * 64;
    int t  = threadIdx.x;
    int wv = t >> 6;                    // wave id: which 32-i tile
    int il = t & 31, h = (t >> 5) & 1;

    {   // stage reciprocal sums (128 threads)
        const f32x4* s4 = (const f32x4*)(s + (size_t)b * Nx);
        f32x4* rs4 = (f32x4*)rs;
        for (int r = t; r < Nx / 4; r += 128) {
            f32x4 v = s4[r];
            rs4[r] = (f32x4){1.0f / v[0], 1.0f / v[1], 1.0f / v[2], 1.0f / v[3]};
        }
    }
    __syncthreads();

    int i32 = i0 + wv * 32;
    // Q as B-operand for E^T, hoisted out of the j-loop
    f16x8 qh[2], ql[2];
#pragma unroll
    for (int ks = 0; ks < 2; ++ks) {
        size_t off = ((size_t)b * Nx + i32 + il) * Dx + h * 8 + ks * 16;
        qh[ks] = *(const f16x8*)(qhi + off);
        ql[ks] = *(const f16x8*)(qlo + off);
    }

    f32x16 acc[2];   // [cg] : out^T tile [c 32][i 32]
    acc[0] = (f32x16){};
    acc[1] = (f32x16){};

    const f16* vbh = vhi + ((size_t)b * Cx + c0) * Nx;
    const f16* vbl = vlo + ((size_t)b * Cx + c0) * Nx;

    for (int jt = 0; jt < 72; ++jt) {
        int j0 = jt * 32;
        // K as A-operand for E^T
        f16x8 kh[2], kl[2];
#pragma unroll
        for (int ks = 0; ks < 2; ++ks) {
            size_t off = ((size_t)b * Nx + j0 + il) * Dx + h * 8 + ks * 16;
            kh[ks] = *(const f16x8*)(khi + off);
            kl[ks] = *(const f16x8*)(klo + off);
        }
        // V as K16 A-operand: lane holds V[c0+cg*32+il][j0 + gp*16 + h*8 + 0..7]
        f16x8 vh8[2][2], vl8[2][2];   // [cg][gp]
#pragma unroll
        for (int cg = 0; cg < 2; ++cg)
#pragma unroll
            for (int gp = 0; gp < 2; ++gp) {
                size_t voff = (size_t)(cg * 32 + il) * Nx + j0 + gp * 16 + h * 8;
                vh8[cg][gp] = *(const f16x8*)(vbh + voff);
                vl8[cg][gp] = *(const f16x8*)(vbl + voff);
            }
        // ---- E^T tile: rows j, cols i ----
        f32x16 e = {};
        __builtin_amdgcn_s_setprio(1);
        e = MFMA_K16(kh[0], qh[0], e);
        e = MFMA_K16(kh[0], ql[0], e);
        e = MFMA_K16(kl[0], qh[0], e);
        e = MFMA_K16(kh[1], qh[1], e);
        e = MFMA_K16(kh[1], ql[1], e);
        e = MFMA_K16(kl[1], qh[1], e);
        __builtin_amdgcn_s_setprio(0);
        // ---- P^T = exp(E^T) * rs[j]; reg 4g+jj holds j = j0+jj+8g+4h ----
        f16x4 ph4[4], pl4[4];
#pragma unroll
        for (int g = 0; g < 4; ++g) {
            f32x4 rsv = *(const f32x4*)&rs[j0 + 8 * g + 4 * h];
#pragma unroll
            for (int jj = 0; jj < 4; ++jj) {
                float p = __expf(e[4 * g + jj]) * rsv[jj];
                f16 hh = (f16)p;
                ph4[g][jj] = hh;
                pl4[g][jj] = (f16)(p - (float)hh);
            }
        }
        // ---- repack K8 frag pairs -> K16 frags (cross-half permlane swap) ----
        f16x8 phK[2], plK[2];
#pragma unroll
        for (int gp = 0; gp < 2; ++gp) {
            phK[gp] = swap_pack(ph4[2 * gp], ph4[2 * gp + 1]);
            plK[gp] = swap_pack(pl4[2 * gp], pl4[2 * gp + 1]);
        }
        // ---- PV: acc[c][i] += V[c][j16-block gp] * P^T[j16-block gp][i] ----
        __builtin_amdgcn_s_setprio(1);
#pragma unroll
        for (int cg = 0; cg < 2; ++cg)
#pragma unroll
            for (int gp = 0; gp < 2; ++gp) {
                acc[cg] = MFMA_K16(vh8[cg][gp], phK[gp], acc[cg]);
                acc[cg] = MFMA_K16(vh8[cg][gp], plK[gp], acc[cg]);
                acc[cg] = MFMA_K16(vl8[cg][gp], phK[gp], acc[cg]);
            }
        __builtin_amdgcn_s_setprio(0);
    }

    // ---- epilogue: D rows are c, cols are i -> coalesced stores ----
    float gm = gamma[0];
#pragma unroll
    for (int cg = 0; cg < 2; ++cg)
#pragma unroll
        for (int r = 0; r < 16; ++r) {
            int c = c0 + cg * 32 + (r & 3) + 8 * (r >> 2) + 4 * h;
            int i = i32 + il;
            size_t idx = ((size_t)b * Cx + c) * Nx + i;
            out[idx] = x[idx] + gm * acc[cg][r];
        }
}

// ---------------------------------------------------------------------------
extern "C" void kernel_launch(void* const* d_in, const int* in_sizes, int n_in,
                              void* d_out, int out_size, void* d_ws, size_t ws_size,
                              hipStream_t stream) {
    const float* x     = (const float*)d_in[0];
    const float* Wq    = (const float*)d_in[1];
    const float* bq    = (const float*)d_in[2];
    const float* Wk    = (const float*)d_in[3];
    const float* bk    = (const float*)d_in[4];
    const float* Wv    = (const float*)d_in[5];
    const float* bv    = (const float*)d_in[6];
    const float* gamma = (const float*)d_in[7];
    float* out = (float*)d_out;

    // ws layout (47.33 MB, unchanged):
    const size_t QK = (size_t)Bx * Nx * Dx;
    const size_t VN = (size_t)Bx * Cx * Nx;
    f16* qhi = (f16*)d_ws;
    f16* qlo = qhi + QK;
    f16* khi = qlo + QK;
    f16* klo = khi + QK;
    f16* vhi = klo + QK;
    f16* vlo = vhi + VN;
    float* s = (float*)(vlo + VN);

    qk_proj  <<<2 * Bx * 4 * 9, 256, 0, stream>>>(x, Wq, bq, Wk, bk, qhi, qlo, khi, klo);
    v_proj   <<<Bx * (Nx / 16), 256, 0, stream>>>(x, Wv, bv, vhi, vlo);
    col_stats<<<Bx * 72,        256, 0, stream>>>(qhi, qlo, khi, klo, s);
    attn_out <<<Bx * 36 * 4,    128, 0, stream>>>(qhi, qlo, khi, klo, vhi, vlo, s, x, gamma, out);
}

// Round 2
// 577.713 us; speedup vs baseline: 1.2351x; 1.2351x over previous
//
#include <hip/hip_runtime.h>

// Shapes (fixed by the problem)
#define Bx 16
#define Cx 256
#define Dx 32
#define Nx 2304   // 48*48

typedef _Float16 f16;
typedef _Float16 f16x4 __attribute__((ext_vector_type(4)));
typedef _Float16 f16x8 __attribute__((ext_vector_type(8)));
typedef float    f32x4 __attribute__((ext_vector_type(4)));
typedef float    f32x16 __attribute__((ext_vector_type(16)));
typedef unsigned int u32x2 __attribute__((ext_vector_type(2)));
typedef unsigned int u32x4 __attribute__((ext_vector_type(4)));

// A,B fragment layouts (gfx950):
//  32x32x16_f16: lane holds A[m=lane%32][k=(lane/32)*8 + 0..7]  (f16x8)
//  C/D 32x32   : col=lane&31, row=(reg&3)+8*(reg>>2)+4*(lane>>5)  [verified]
#define MFMA_K16(a, b, c) __builtin_amdgcn_mfma_f32_32x32x16_f16((a), (b), (c), 0, 0, 0)
#define EXP2F(x) __builtin_amdgcn_exp2f(x)

// Repack two f16x4 B-frags of the K8 layout (j-granularity 4 per lane-half)
// into one f16x8 B-frag of the K16 layout (j-granularity 8 per lane-half).
// (R1-verified correct.)
__device__ __forceinline__ f16x8 swap_pack(f16x4 a, f16x4 b) {
    u32x2 au = __builtin_bit_cast(u32x2, a);
    u32x2 bu = __builtin_bit_cast(u32x2, b);
    unsigned a0 = au[0], a1 = au[1], b0 = bu[0], b1 = bu[1];
    asm("v_permlane32_swap_b32 %0, %1" : "+v"(a0), "+v"(b0));
    asm("v_permlane32_swap_b32 %0, %1" : "+v"(a1), "+v"(b1));
    u32x4 r = {a0, a1, b0, b1};
    return __builtin_bit_cast(f16x8, r);
}

// ---------------------------------------------------------------------------
// Kernel A: q/k projections -> f16 hi/lo, layout [b][n][d] (d contiguous).
// NEW: q is pre-scaled by 1/ln2 so downstream softmax uses exp2 (v_exp_f32)
// directly, removing one v_mul per softmax element.
// ---------------------------------------------------------------------------
__global__ __launch_bounds__(256) void qk_proj(
    const float* __restrict__ x,
    const float* __restrict__ Wq, const float* __restrict__ bq,
    const float* __restrict__ Wk, const float* __restrict__ bk,
    f16* __restrict__ qhi, f16* __restrict__ qlo,
    f16* __restrict__ khi, f16* __restrict__ klo) {
    int bid = blockIdx.x;
    int nt = bid % 9;  bid /= 9;
    int dc = bid % 4;  bid /= 4;
    int b  = bid % Bx; bid /= Bx;
    int qk = bid;  // 0 -> q, 1 -> k
    const float* Wm   = qk ? Wk : Wq;
    const float* bias = qk ? bk : bq;
    f16* dhi          = qk ? khi : qhi;
    f16* dlo          = qk ? klo : qlo;
    float sc          = qk ? 1.0f : 1.4426950408889634f;  // q *= 1/ln2

    int n  = nt * 256 + threadIdx.x;
    int d0 = dc * 8;
    float acc[8];
#pragma unroll
    for (int dd = 0; dd < 8; ++dd) acc[dd] = bias[d0 + dd];

    const float* xcol = x + (size_t)b * Cx * Nx + n;
    for (int c = 0; c < Cx; ++c) {
        float xv = xcol[(size_t)c * Nx];
#pragma unroll
        for (int dd = 0; dd < 8; ++dd)
            acc[dd] += Wm[(d0 + dd) * Cx + c] * xv;
    }
    f16x8 hi, lo;
#pragma unroll
    for (int dd = 0; dd < 8; ++dd) {
        float a = acc[dd] * sc;
        f16 h = (f16)a;
        hi[dd] = h;
        lo[dd] = (f16)(a - (float)h);
    }
    size_t base = ((size_t)b * Nx + n) * Dx + d0;
    *(f16x8*)(dhi + base) = hi;
    *(f16x8*)(dlo + base) = lo;
}

// ---------------------------------------------------------------------------
// Kernel B: v projection -> f16 hi/lo, layout [b][c][n] (n contiguous).
// (unchanged — passed)
// ---------------------------------------------------------------------------
__global__ __launch_bounds__(256) void v_proj(
    const float* __restrict__ x,
    const float* __restrict__ Wv, const float* __restrict__ bv,
    f16* __restrict__ vhi, f16* __restrict__ vlo) {
    __shared__ float sx[Cx * 16];
    int bid = blockIdx.x;
    int nt = bid % (Nx / 16);
    int b  = bid / (Nx / 16);
    int n0 = nt * 16;
    int t  = threadIdx.x;

    for (int r = 0; r < 16; ++r) {
        int f = r * 256 + t;
        int c = f >> 4, nn = f & 15;
        sx[f] = x[((size_t)b * Cx + c) * Nx + n0 + nn];
    }
    __syncthreads();

    float acc[16];
    float bvv = bv[t];
#pragma unroll
    for (int nn = 0; nn < 16; ++nn) acc[nn] = bvv;

    const float* wrow = Wv + (size_t)t * Cx;
    for (int c = 0; c < Cx; ++c) {
        float wv = wrow[c];
        const float4* sxr = (const float4*)&sx[c * 16];
#pragma unroll
        for (int g = 0; g < 4; ++g) {
            float4 xv = sxr[g];
            acc[g * 4 + 0] += wv * xv.x;
            acc[g * 4 + 1] += wv * xv.y;
            acc[g * 4 + 2] += wv * xv.z;
            acc[g * 4 + 3] += wv * xv.w;
        }
    }
    f16x8 h0, l0, h1, l1;
#pragma unroll
    for (int nn = 0; nn < 8; ++nn) {
        f16 h = (f16)acc[nn];
        h0[nn] = h; l0[nn] = (f16)(acc[nn] - (float)h);
    }
#pragma unroll
    for (int nn = 0; nn < 8; ++nn) {
        f16 h = (f16)acc[8 + nn];
        h1[nn] = h; l1[nn] = (f16)(acc[8 + nn] - (float)h);
    }
    size_t base = ((size_t)b * Cx + t) * Nx + n0;
    *(f16x8*)(vhi + base)     = h0;
    *(f16x8*)(vhi + base + 8) = h1;
    *(f16x8*)(vlo + base)     = l0;
    *(f16x8*)(vlo + base + 8) = l1;
}

// ---------------------------------------------------------------------------
// Kernel C: softmax column sums  s[b][j] = sum_i exp(E[i,j]).
// 4 waves per block, each covering 18 of the 72 i-tiles; LDS partial reduce.
// grid: Bx * 72 blocks, 256 threads.  (exp -> exp2, q pre-scaled)
// ---------------------------------------------------------------------------
__global__ __launch_bounds__(256, 4) void col_stats(
    const f16* __restrict__ qhi, const f16* __restrict__ qlo,
    const f16* __restrict__ khi, const f16* __restrict__ klo,
    float* __restrict__ s) {
    __shared__ float part[4][32];
    int jt = blockIdx.x % 72;
    int b  = blockIdx.x / 72;
    int j0 = jt * 32;
    int t  = threadIdx.x;
    int w  = t >> 6;              // wave id 0..3
    int il = t & 31, h = (t >> 5) & 1;

    f16x8 kh[2], kl[2];
#pragma unroll
    for (int ks = 0; ks < 2; ++ks) {
        size_t off = ((size_t)b * Nx + j0 + il) * Dx + h * 8 + ks * 16;
        kh[ks] = *(const f16x8*)(khi + off);
        kl[ks] = *(const f16x8*)(klo + off);
    }
    f32x16 sacc = {};
    for (int it = w * 18; it < w * 18 + 18; ++it) {
        f16x8 qh[2], ql[2];
#pragma unroll
        for (int ks = 0; ks < 2; ++ks) {
            size_t off = ((size_t)b * Nx + it * 32 + il) * Dx + h * 8 + ks * 16;
            qh[ks] = *(const f16x8*)(qhi + off);
            ql[ks] = *(const f16x8*)(qlo + off);
        }
        f32x16 e = {};
        __builtin_amdgcn_s_setprio(1);
        e = MFMA_K16(kh[0], qh[0], e);
        e = MFMA_K16(kh[0], ql[0], e);
        e = MFMA_K16(kl[0], qh[0], e);
        e = MFMA_K16(kh[1], qh[1], e);
        e = MFMA_K16(kh[1], ql[1], e);
        e = MFMA_K16(kl[1], qh[1], e);
        __builtin_amdgcn_s_setprio(0);
#pragma unroll
        for (int r = 0; r < 16; ++r) sacc[r] += EXP2F(e[r]);
    }
#pragma unroll
    for (int r = 0; r < 16; ++r) {
        float v = sacc[r];
        for (int msk = 1; msk <= 16; msk <<= 1) v += __shfl_xor(v, msk);
        if (il == 0) part[w][(r & 3) + 8 * (r >> 2) + 4 * h] = v;
    }
    __syncthreads();
    if (t < 32)
        s[(size_t)b * Nx + j0 + t] =
            part[0][t] + part[1][t] + part[2][t] + part[3][t];
}

// ---------------------------------------------------------------------------
// Kernel D: main.  R0 shape (64 threads, 2 i-tiles/wave, lb(64,2) -> 256-reg
// budget) + K16 PV + register pipelining:
//  - K double-buffered in regs: j+1's K issued at top of iteration j.
//  - V single-buffered: j+1's V issued right after the last PV read of j;
//    the E+exp phase of j+1 (~400 cyc) covers L2 latency.
//  - unroll 2 keeps all buffer indices compile-time static (no scratch).
// grid: Bx * 36 * 4 = 2304 blocks, 64 threads.
// ---------------------------------------------------------------------------
__global__ __launch_bounds__(64, 2) void attn_out(
    const f16* __restrict__ qhi, const f16* __restrict__ qlo,
    const f16* __restrict__ khi, const f16* __restrict__ klo,
    const f16* __restrict__ vhi, const f16* __restrict__ vlo,
    const float* __restrict__ s, const float* __restrict__ x,
    const float* __restrict__ gamma, float* __restrict__ out) {
    __shared__ __align__(16) float rs[Nx];   // 9216 B: 1/s for this batch
    int blk = blockIdx.x;
    int w4   = blk & 3;  blk >>= 2;     // c-quarter
    int it64 = blk % 36;
    int b    = blk / 36;
    int i0   = it64 * 64;
    int c0   = w4 * 64;
    int t = threadIdx.x, il = t & 31, h = t >> 5;

    {   // stage reciprocal sums
        const f32x4* s4 = (const f32x4*)(s + (size_t)b * Nx);
        f32x4* rs4 = (f32x4*)rs;
        for (int r = t; r < Nx / 4; r += 64) {
            f32x4 v = s4[r];
            rs4[r] = (f32x4){1.0f / v[0], 1.0f / v[1], 1.0f / v[2], 1.0f / v[3]};
        }
    }
    __syncthreads();

    // Q as B-operand for E^T, both i-subtiles, hoisted out of the j-loop
    f16x8 qh[2][2], ql[2][2];   // [itile][ks]
#pragma unroll
    for (int itile = 0; itile < 2; ++itile)
#pragma unroll
        for (int ks = 0; ks < 2; ++ks) {
            size_t off = ((size_t)b * Nx + i0 + itile * 32 + il) * Dx + h * 8 + ks * 16;
            qh[itile][ks] = *(const f16x8*)(qhi + off);
            ql[itile][ks] = *(const f16x8*)(qlo + off);
        }

    f32x16 acc[2][2];  // [itile][cg] : out^T tile [c 32][i 32]
#pragma unroll
    for (int a = 0; a < 2; ++a)
#pragma unroll
        for (int cgi = 0; cgi < 2; ++cgi) acc[a][cgi] = (f32x16){};

    // per-wave base pointers (only the j offset varies in the loop)
    const f16* kph = khi + ((size_t)b * Nx + il) * Dx + h * 8;
    const f16* kpl = klo + ((size_t)b * Nx + il) * Dx + h * 8;
    const f16* vph = vhi + ((size_t)b * Cx + c0 + il) * Nx + h * 8;
    const f16* vpl = vlo + ((size_t)b * Cx + c0 + il) * Nx + h * 8;

    // K register double-buffer, V register single-buffer
    f16x8 kh[2][2], kl[2][2];    // [buf][ks]
    f16x8 vh8[2][2], vl8[2][2];  // [cg][gp]

    // prologue: K tile 0 into buf 0, V tile 0
#pragma unroll
    for (int ks = 0; ks < 2; ++ks) {
        kh[0][ks] = *(const f16x8*)(kph + ks * 16);
        kl[0][ks] = *(const f16x8*)(kpl + ks * 16);
    }
#pragma unroll
    for (int cg = 0; cg < 2; ++cg)
#pragma unroll
        for (int gp = 0; gp < 2; ++gp) {
            size_t voff = (size_t)cg * 32 * Nx + gp * 16;
            vh8[cg][gp] = *(const f16x8*)(vph + voff);
            vl8[cg][gp] = *(const f16x8*)(vpl + voff);
        }

#pragma unroll 2
    for (int jt = 0; jt < 72; ++jt) {
        int cur = jt & 1, nxt = cur ^ 1;
        int j0  = jt * 32;
        // ---- prefetch K(j+1) into the other buffer (wraps harmlessly) ----
        int kn = (jt + 1 < 72) ? (jt + 1) * 1024 : 0;  // j*Dx in f16 elems
#pragma unroll
        for (int ks = 0; ks < 2; ++ks) {
            kh[nxt][ks] = *(const f16x8*)(kph + kn + ks * 16);
            kl[nxt][ks] = *(const f16x8*)(kpl + kn + ks * 16);
        }
#pragma unroll
        for (int itile = 0; itile < 2; ++itile) {
            // ---- E^T tile: rows j, cols i ----
            f32x16 e = {};
            __builtin_amdgcn_s_setprio(1);
            e = MFMA_K16(kh[cur][0], qh[itile][0], e);
            e = MFMA_K16(kh[cur][0], ql[itile][0], e);
            e = MFMA_K16(kl[cur][0], qh[itile][0], e);
            e = MFMA_K16(kh[cur][1], qh[itile][1], e);
            e = MFMA_K16(kh[cur][1], ql[itile][1], e);
            e = MFMA_K16(kl[cur][1], qh[itile][1], e);
            __builtin_amdgcn_s_setprio(0);
            // ---- P^T = exp2(E^T) * rs[j]; reg 4g+jj holds j = j0+jj+8g+4h ----
            f16x4 ph4[4], pl4[4];
#pragma unroll
            for (int g = 0; g < 4; ++g) {
                f32x4 rsv = *(const f32x4*)&rs[j0 + 8 * g + 4 * h];
#pragma unroll
                for (int jj = 0; jj < 4; ++jj) {
                    float p = EXP2F(e[4 * g + jj]) * rsv[jj];
                    f16 hh = (f16)p;
                    ph4[g][jj] = hh;
                    pl4[g][jj] = (f16)(p - (float)hh);
                }
            }
            // ---- repack K8 frag pairs -> K16 frags ----
            f16x8 phK[2], plK[2];
#pragma unroll
            for (int gp = 0; gp < 2; ++gp) {
                phK[gp] = swap_pack(ph4[2 * gp], ph4[2 * gp + 1]);
                plK[gp] = swap_pack(pl4[2 * gp], pl4[2 * gp + 1]);
            }
            // ---- PV: acc[c][i] += V[c][j16-block gp] * P^T[j16-block gp][i] ----
            __builtin_amdgcn_s_setprio(1);
#pragma unroll
            for (int cg = 0; cg < 2; ++cg)
#pragma unroll
                for (int gp = 0; gp < 2; ++gp) {
                    acc[itile][cg] = MFMA_K16(vh8[cg][gp], phK[gp], acc[itile][cg]);
                    acc[itile][cg] = MFMA_K16(vh8[cg][gp], plK[gp], acc[itile][cg]);
                    acc[itile][cg] = MFMA_K16(vl8[cg][gp], phK[gp], acc[itile][cg]);
                }
            __builtin_amdgcn_s_setprio(0);
        }
        // ---- late-issue V(j+1) into the same registers (after last PV read);
        //      consumed only after next iteration's E+exp phase ----
        int vn = (jt + 1 < 72) ? (jt + 1) * 32 : 0;   // j in f16 elems
#pragma unroll
        for (int cg = 0; cg < 2; ++cg)
#pragma unroll
            for (int gp = 0; gp < 2; ++gp) {
                size_t voff = (size_t)cg * 32 * Nx + vn + gp * 16;
                vh8[cg][gp] = *(const f16x8*)(vph + voff);
                vl8[cg][gp] = *(const f16x8*)(vpl + voff);
            }
    }

    // ---- epilogue: D rows are c, cols are i -> stores already coalesced ----
    float gm = gamma[0];
#pragma unroll
    for (int itile = 0; itile < 2; ++itile)
#pragma unroll
        for (int cg = 0; cg < 2; ++cg)
#pragma unroll
            for (int r = 0; r < 16; ++r) {
                int c = c0 + cg * 32 + (r & 3) + 8 * (r >> 2) + 4 * h;
                int i = i0 + itile * 32 + il;
                size_t idx = ((size_t)b * Cx + c) * Nx + i;
                out[idx] = x[idx] + gm * acc[itile][cg][r];
            }
}

// ---------------------------------------------------------------------------
extern "C" void kernel_launch(void* const* d_in, const int* in_sizes, int n_in,
                              void* d_out, int out_size, void* d_ws, size_t ws_size,
                              hipStream_t stream) {
    const float* x     = (const float*)d_in[0];
    const float* Wq    = (const float*)d_in[1];
    const float* bq    = (const float*)d_in[2];
    const float* Wk    = (const float*)d_in[3];
    const float* bk    = (const float*)d_in[4];
    const float* Wv    = (const float*)d_in[5];
    const float* bv    = (const float*)d_in[6];
    const float* gamma = (const float*)d_in[7];
    float* out = (float*)d_out;

    const size_t QK = (size_t)Bx * Nx * Dx;
    const size_t VN = (size_t)Bx * Cx * Nx;
    f16* qhi = (f16*)d_ws;
    f16* qlo = qhi + QK;
    f16* khi = qlo + QK;
    f16* klo = khi + QK;
    f16* vhi = klo + QK;
    f16* vlo = vhi + VN;
    float* s = (float*)(vlo + VN);

    qk_proj  <<<2 * Bx * 4 * 9, 256, 0, stream>>>(x, Wq, bq, Wk, bk, qhi, qlo, khi, klo);
    v_proj   <<<Bx * (Nx / 16), 256, 0, stream>>>(x, Wv, bv, vhi, vlo);
    col_stats<<<Bx * 72,        256, 0, stream>>>(qhi, qlo, khi, klo, s);
    attn_out <<<Bx * 36 * 4,    64, 0, stream>>>(qhi, qlo, khi, klo, vhi, vlo, s, x, gamma, out);
}

// Round 5
// 538.351 us; speedup vs baseline: 1.3254x; 1.0731x over previous
//
#include <hip/hip_runtime.h>

// Shapes (fixed by the problem)
#define Bx 16
#define Cx 256
#define Dx 32
#define Nx 2304   // 48*48

typedef _Float16 f16;
typedef _Float16 f16x4 __attribute__((ext_vector_type(4)));
typedef _Float16 f16x8 __attribute__((ext_vector_type(8)));
typedef float    f32x4 __attribute__((ext_vector_type(4)));
typedef float    f32x16 __attribute__((ext_vector_type(16)));
typedef unsigned int u32x2 __attribute__((ext_vector_type(2)));
typedef unsigned int u32x4 __attribute__((ext_vector_type(4)));

// A,B fragment layouts (gfx950):
//  32x32x16_f16: lane holds A[m=lane%32][k=(lane/32)*8 + 0..7]  (f16x8)
//  C/D 32x32   : col=lane&31, row=(reg&3)+8*(reg>>2)+4*(lane>>5)  [verified]
#define MFMA_K16(a, b, c) __builtin_amdgcn_mfma_f32_32x32x16_f16((a), (b), (c), 0, 0, 0)
#define EXP2F(x) __builtin_amdgcn_exp2f(x)

// Repack two f16x4 B-frags of the K8 layout (j-granularity 4 per lane-half)
// into one f16x8 B-frag of the K16 layout (j-granularity 8 per lane-half).
// (R1/R2-verified correct.)
__device__ __forceinline__ f16x8 swap_pack(f16x4 a, f16x4 b) {
    u32x2 au = __builtin_bit_cast(u32x2, a);
    u32x2 bu = __builtin_bit_cast(u32x2, b);
    unsigned a0 = au[0], a1 = au[1], b0 = bu[0], b1 = bu[1];
    asm("v_permlane32_swap_b32 %0, %1" : "+v"(a0), "+v"(b0));
    asm("v_permlane32_swap_b32 %0, %1" : "+v"(a1), "+v"(b1));
    u32x4 r = {a0, a1, b0, b1};
    return __builtin_bit_cast(f16x8, r);
}

// ---------------------------------------------------------------------------
// Kernel A: q/k projections -> f16 hi/lo, layout [b][n][d] (d contiguous).
// q pre-scaled by 1/ln2 so softmax uses exp2 directly. (R2-passing, unchanged)
// ---------------------------------------------------------------------------
__global__ __launch_bounds__(256) void qk_proj(
    const float* __restrict__ x,
    const float* __restrict__ Wq, const float* __restrict__ bq,
    const float* __restrict__ Wk, const float* __restrict__ bk,
    f16* __restrict__ qhi, f16* __restrict__ qlo,
    f16* __restrict__ khi, f16* __restrict__ klo) {
    int bid = blockIdx.x;
    int nt = bid % 9;  bid /= 9;
    int dc = bid % 4;  bid /= 4;
    int b  = bid % Bx; bid /= Bx;
    int qk = bid;  // 0 -> q, 1 -> k
    const float* Wm   = qk ? Wk : Wq;
    const float* bias = qk ? bk : bq;
    f16* dhi          = qk ? khi : qhi;
    f16* dlo          = qk ? klo : qlo;
    float sc          = qk ? 1.0f : 1.4426950408889634f;  // q *= 1/ln2

    int n  = nt * 256 + threadIdx.x;
    int d0 = dc * 8;
    float acc[8];
#pragma unroll
    for (int dd = 0; dd < 8; ++dd) acc[dd] = bias[d0 + dd];

    const float* xcol = x + (size_t)b * Cx * Nx + n;
    for (int c = 0; c < Cx; ++c) {
        float xv = xcol[(size_t)c * Nx];
#pragma unroll
        for (int dd = 0; dd < 8; ++dd)
            acc[dd] += Wm[(d0 + dd) * Cx + c] * xv;
    }
    f16x8 hi, lo;
#pragma unroll
    for (int dd = 0; dd < 8; ++dd) {
        float a = acc[dd] * sc;
        f16 h = (f16)a;
        hi[dd] = h;
        lo[dd] = (f16)(a - (float)h);
    }
    size_t base = ((size_t)b * Nx + n) * Dx + d0;
    *(f16x8*)(dhi + base) = hi;
    *(f16x8*)(dlo + base) = lo;
}

// ---------------------------------------------------------------------------
// Kernel B: v projection -> f16 hi/lo, layout [b][c][n]. (R2-passing, unchanged)
// ---------------------------------------------------------------------------
__global__ __launch_bounds__(256) void v_proj(
    const float* __restrict__ x,
    const float* __restrict__ Wv, const float* __restrict__ bv,
    f16* __restrict__ vhi, f16* __restrict__ vlo) {
    __shared__ float sx[Cx * 16];
    int bid = blockIdx.x;
    int nt = bid % (Nx / 16);
    int b  = bid / (Nx / 16);
    int n0 = nt * 16;
    int t  = threadIdx.x;

    for (int r = 0; r < 16; ++r) {
        int f = r * 256 + t;
        int c = f >> 4, nn = f & 15;
        sx[f] = x[((size_t)b * Cx + c) * Nx + n0 + nn];
    }
    __syncthreads();

    float acc[16];
    float bvv = bv[t];
#pragma unroll
    for (int nn = 0; nn < 16; ++nn) acc[nn] = bvv;

    const float* wrow = Wv + (size_t)t * Cx;
    for (int c = 0; c < Cx; ++c) {
        float wv = wrow[c];
        const float4* sxr = (const float4*)&sx[c * 16];
#pragma unroll
        for (int g = 0; g < 4; ++g) {
            float4 xv = sxr[g];
            acc[g * 4 + 0] += wv * xv.x;
            acc[g * 4 + 1] += wv * xv.y;
            acc[g * 4 + 2] += wv * xv.z;
            acc[g * 4 + 3] += wv * xv.w;
        }
    }
    f16x8 h0, l0, h1, l1;
#pragma unroll
    for (int nn = 0; nn < 8; ++nn) {
        f16 h = (f16)acc[nn];
        h0[nn] = h; l0[nn] = (f16)(acc[nn] - (float)h);
    }
#pragma unroll
    for (int nn = 0; nn < 8; ++nn) {
        f16 h = (f16)acc[8 + nn];
        h1[nn] = h; l1[nn] = (f16)(acc[8 + nn] - (float)h);
    }
    size_t base = ((size_t)b * Cx + t) * Nx + n0;
    *(f16x8*)(vhi + base)     = h0;
    *(f16x8*)(vhi + base + 8) = h1;
    *(f16x8*)(vlo + base)     = l0;
    *(f16x8*)(vlo + base + 8) = l1;
}

// ---------------------------------------------------------------------------
// Kernel C: softmax column sums  s[b][j] = sum_i exp2(E[i,j]).
// 4 waves per block, LDS partial reduce. (R2-passing, unchanged)
// ---------------------------------------------------------------------------
__global__ __launch_bounds__(256, 4) void col_stats(
    const f16* __restrict__ qhi, const f16* __restrict__ qlo,
    const f16* __restrict__ khi, const f16* __restrict__ klo,
    float* __restrict__ s) {
    __shared__ float part[4][32];
    int jt = blockIdx.x % 72;
    int b  = blockIdx.x / 72;
    int j0 = jt * 32;
    int t  = threadIdx.x;
    int w  = t >> 6;              // wave id 0..3
    int il = t & 31, h = (t >> 5) & 1;

    f16x8 kh[2], kl[2];
#pragma unroll
    for (int ks = 0; ks < 2; ++ks) {
        size_t off = ((size_t)b * Nx + j0 + il) * Dx + h * 8 + ks * 16;
        kh[ks] = *(const f16x8*)(khi + off);
        kl[ks] = *(const f16x8*)(klo + off);
    }
    f32x16 sacc = {};
    for (int it = w * 18; it < w * 18 + 18; ++it) {
        f16x8 qh[2], ql[2];
#pragma unroll
        for (int ks = 0; ks < 2; ++ks) {
            size_t off = ((size_t)b * Nx + it * 32 + il) * Dx + h * 8 + ks * 16;
            qh[ks] = *(const f16x8*)(qhi + off);
            ql[ks] = *(const f16x8*)(qlo + off);
        }
        f32x16 e = {};
        __builtin_amdgcn_s_setprio(1);
        e = MFMA_K16(kh[0], qh[0], e);
        e = MFMA_K16(kh[0], ql[0], e);
        e = MFMA_K16(kl[0], qh[0], e);
        e = MFMA_K16(kh[1], qh[1], e);
        e = MFMA_K16(kh[1], ql[1], e);
        e = MFMA_K16(kl[1], qh[1], e);
        __builtin_amdgcn_s_setprio(0);
#pragma unroll
        for (int r = 0; r < 16; ++r) sacc[r] += EXP2F(e[r]);
    }
#pragma unroll
    for (int r = 0; r < 16; ++r) {
        float v = sacc[r];
        for (int msk = 1; msk <= 16; msk <<= 1) v += __shfl_xor(v, msk);
        if (il == 0) part[w][(r & 3) + 8 * (r >> 2) + 4 * h] = v;
    }
    __syncthreads();
    if (t < 32)
        s[(size_t)b * Nx + j0 + t] =
            part[0][t] + part[1][t] + part[2][t] + part[3][t];
}

// ---------------------------------------------------------------------------
// Kernel D: main.  R4: minimal-diff occupancy fix over the R2-passing kernel.
// 128 threads = 2 waves; wave jh processes j in [jh*1152, jh*1152+1152) for
// BOTH itiles (per-wave register structure identical to R2, 36 j-iters).
// Partials combine by addition via one padded-LDS exchange (softmax denom is
// global and precomputed). Wave count 2304 -> 4608, per-wave chain halved.
// launch_bounds(128,2): same 256-reg budget as the passing R2 kernel.
// grid: Bx * 36 * 4 = 2304 blocks, 128 threads.
// ---------------------------------------------------------------------------
__global__ __launch_bounds__(128, 2) void attn_out(
    const f16* __restrict__ qhi, const f16* __restrict__ qlo,
    const f16* __restrict__ khi, const f16* __restrict__ klo,
    const f16* __restrict__ vhi, const f16* __restrict__ vlo,
    const float* __restrict__ s, const float* __restrict__ x,
    const float* __restrict__ gamma, float* __restrict__ out) {
    __shared__ __align__(16) float rs[Nx];     // 9216 B: 1/s for this batch
    __shared__ float red[2][64][33];           // 16896 B, padded
    int blk = blockIdx.x;
    int w4   = blk & 3;  blk >>= 2;     // c-quarter
    int it64 = blk % 36;
    int b    = blk / 36;
    int i0   = it64 * 64;
    int c0   = w4 * 64;
    int t = threadIdx.x;
    int jh   = t >> 6;                  // wave id = j-half (0..1)
    int lane = t & 63;
    int il = t & 31, h = (t >> 5) & 1;

    {   // stage reciprocal sums (128 threads)
        const f32x4* s4 = (const f32x4*)(s + (size_t)b * Nx);
        f32x4* rs4 = (f32x4*)rs;
        for (int r = t; r < Nx / 4; r += 128) {
            f32x4 v = s4[r];
            rs4[r] = (f32x4){1.0f / v[0], 1.0f / v[1], 1.0f / v[2], 1.0f / v[3]};
        }
    }
    __syncthreads();

    // Q as B-operand for E^T, both i-subtiles, hoisted out of the j-loop
    f16x8 qh[2][2], ql[2][2];   // [itile][ks]
#pragma unroll
    for (int itile = 0; itile < 2; ++itile)
#pragma unroll
        for (int ks = 0; ks < 2; ++ks) {
            size_t off = ((size_t)b * Nx + i0 + itile * 32 + il) * Dx + h * 8 + ks * 16;
            qh[itile][ks] = *(const f16x8*)(qhi + off);
            ql[itile][ks] = *(const f16x8*)(qlo + off);
        }

    f32x16 acc[2][2];  // [itile][cg] : out^T tile partial (this j-half)
#pragma unroll
    for (int a = 0; a < 2; ++a)
#pragma unroll
        for (int cgi = 0; cgi < 2; ++cgi) acc[a][cgi] = (f32x16){};

    // per-wave base pointers: j window = [jh*1152, jh*1152+1152)
    int jb = jh * 36 * 32;
    const f16* kph = khi + ((size_t)b * Nx + jb + il) * Dx + h * 8;
    const f16* kpl = klo + ((size_t)b * Nx + jb + il) * Dx + h * 8;
    const f16* vph = vhi + ((size_t)b * Cx + c0 + il) * Nx + jb + h * 8;
    const f16* vpl = vlo + ((size_t)b * Cx + c0 + il) * Nx + jb + h * 8;

    // K register double-buffer, V register single-buffer (late prefetch)
    f16x8 kh[2][2], kl[2][2];    // [buf][ks]
    f16x8 vh8[2][2], vl8[2][2];  // [cg][gp]

    // prologue: K tile 0 into buf 0, V tile 0
#pragma unroll
    for (int ks = 0; ks < 2; ++ks) {
        kh[0][ks] = *(const f16x8*)(kph + ks * 16);
        kl[0][ks] = *(const f16x8*)(kpl + ks * 16);
    }
#pragma unroll
    for (int cg = 0; cg < 2; ++cg)
#pragma unroll
        for (int gp = 0; gp < 2; ++gp) {
            size_t voff = (size_t)cg * 32 * Nx + gp * 16;
            vh8[cg][gp] = *(const f16x8*)(vph + voff);
            vl8[cg][gp] = *(const f16x8*)(vpl + voff);
        }

#pragma unroll 2
    for (int jt = 0; jt < 36; ++jt) {
        int cur = jt & 1, nxt = cur ^ 1;
        int j0  = jb + jt * 32;          // global j for rs indexing
        // ---- prefetch K(jt+1) into the other buffer (wraps harmlessly) ----
        int kn = (jt + 1 < 36) ? (jt + 1) * 1024 : 0;  // 32*Dx f16 per j-tile
#pragma unroll
        for (int ks = 0; ks < 2; ++ks) {
            kh[nxt][ks] = *(const f16x8*)(kph + kn + ks * 16);
            kl[nxt][ks] = *(const f16x8*)(kpl + kn + ks * 16);
        }
#pragma unroll
        for (int itile = 0; itile < 2; ++itile) {
            // ---- E^T tile: rows j, cols i ----
            f32x16 e = {};
            __builtin_amdgcn_s_setprio(1);
            e = MFMA_K16(kh[cur][0], qh[itile][0], e);
            e = MFMA_K16(kh[cur][0], ql[itile][0], e);
            e = MFMA_K16(kl[cur][0], qh[itile][0], e);
            e = MFMA_K16(kh[cur][1], qh[itile][1], e);
            e = MFMA_K16(kh[cur][1], ql[itile][1], e);
            e = MFMA_K16(kl[cur][1], qh[itile][1], e);
            __builtin_amdgcn_s_setprio(0);
            // ---- P^T = exp2(E^T) * rs[j]; reg 4g+jj holds j = j0+jj+8g+4h ----
            f16x4 ph4[4], pl4[4];
#pragma unroll
            for (int g = 0; g < 4; ++g) {
                f32x4 rsv = *(const f32x4*)&rs[j0 + 8 * g + 4 * h];
#pragma unroll
                for (int jj = 0; jj < 4; ++jj) {
                    float p = EXP2F(e[4 * g + jj]) * rsv[jj];
                    f16 hh = (f16)p;
                    ph4[g][jj] = hh;
                    pl4[g][jj] = (f16)(p - (float)hh);
                }
            }
            // ---- repack K8 frag pairs -> K16 frags ----
            f16x8 phK[2], plK[2];
#pragma unroll
            for (int gp = 0; gp < 2; ++gp) {
                phK[gp] = swap_pack(ph4[2 * gp], ph4[2 * gp + 1]);
                plK[gp] = swap_pack(pl4[2 * gp], pl4[2 * gp + 1]);
            }
            // ---- PV: acc[c][i] += V[c][j16-block gp] * P^T[j16-block gp][i] ----
            __builtin_amdgcn_s_setprio(1);
#pragma unroll
            for (int cg = 0; cg < 2; ++cg)
#pragma unroll
                for (int gp = 0; gp < 2; ++gp) {
                    acc[itile][cg] = MFMA_K16(vh8[cg][gp], phK[gp], acc[itile][cg]);
                    acc[itile][cg] = MFMA_K16(vh8[cg][gp], plK[gp], acc[itile][cg]);
                    acc[itile][cg] = MFMA_K16(vl8[cg][gp], phK[gp], acc[itile][cg]);
                }
            __builtin_amdgcn_s_setprio(0);
        }
        // ---- late-issue V(jt+1) into the same registers (after last PV read)
        int vn = (jt + 1 < 36) ? (jt + 1) * 32 : 0;
#pragma unroll
        for (int cg = 0; cg < 2; ++cg)
#pragma unroll
            for (int gp = 0; gp < 2; ++gp) {
                size_t voff = (size_t)cg * 32 * Nx + vn + gp * 16;
                vh8[cg][gp] = *(const f16x8*)(vph + voff);
                vl8[cg][gp] = *(const f16x8*)(vpl + voff);
            }
    }

    // ---- combine j-halves via LDS, then store (jh==0 wave) ----
    if (jh == 1) {
#pragma unroll
        for (int itile = 0; itile < 2; ++itile)
#pragma unroll
            for (int cg = 0; cg < 2; ++cg)
#pragma unroll
                for (int r = 0; r < 16; ++r)
                    red[itile][lane][cg * 16 + r] = acc[itile][cg][r];
    }
    __syncthreads();
    if (jh == 0) {
        float gm = gamma[0];
#pragma unroll
        for (int itile = 0; itile < 2; ++itile)
#pragma unroll
            for (int cg = 0; cg < 2; ++cg)
#pragma unroll
                for (int r = 0; r < 16; ++r) {
                    int c = c0 + cg * 32 + (r & 3) + 8 * (r >> 2) + 4 * h;
                    int i = i0 + itile * 32 + il;
                    size_t idx = ((size_t)b * Cx + c) * Nx + i;
                    out[idx] = x[idx] +
                        gm * (acc[itile][cg][r] + red[itile][lane][cg * 16 + r]);
                }
    }
}

// ---------------------------------------------------------------------------
extern "C" void kernel_launch(void* const* d_in, const int* in_sizes, int n_in,
                              void* d_out, int out_size, void* d_ws, size_t ws_size,
                              hipStream_t stream) {
    const float* x     = (const float*)d_in[0];
    const float* Wq    = (const float*)d_in[1];
    const float* bq    = (const float*)d_in[2];
    const float* Wk    = (const float*)d_in[3];
    const float* bk    = (const float*)d_in[4];
    const float* Wv    = (const float*)d_in[5];
    const float* bv    = (const float*)d_in[6];
    const float* gamma = (const float*)d_in[7];
    float* out = (float*)d_out;

    const size_t QK = (size_t)Bx * Nx * Dx;
    const size_t VN = (size_t)Bx * Cx * Nx;
    f16* qhi = (f16*)d_ws;
    f16* qlo = qhi + QK;
    f16* khi = qlo + QK;
    f16* klo = khi + QK;
    f16* vhi = klo + QK;
    f16* vlo = vhi + VN;
    float* s = (float*)(vlo + VN);

    qk_proj  <<<2 * Bx * 4 * 9, 256, 0, stream>>>(x, Wq, bq, Wk, bk, qhi, qlo, khi, klo);
    v_proj   <<<Bx * (Nx / 16), 256, 0, stream>>>(x, Wv, bv, vhi, vlo);
    col_stats<<<Bx * 72,        256, 0, stream>>>(qhi, qlo, khi, klo, s);
    attn_out <<<Bx * 36 * 4,    128, 0, stream>>>(qhi, qlo, khi, klo, vhi, vlo, s, x, gamma, out);
}